// Round 3
// baseline (269.394 us; speedup 1.0000x reference)
//
#include <hip/hip_runtime.h>

// ArcFace loss, MI355X. B=512, D=512, C=64000, s=64, m=0.5.
// R3: W read exactly ONCE. Each block owns 64 classes: phase 0 loads the
// fp32 W rows, normalizes, stores bf16 into LDS (resident B operand,
// XOR-swizzled); K-loop stages only A (x-hat) via dbuf global_load_lds.
// No Wn global round-trip (removes ~130 MB of HBM traffic vs R2).

#define B_N 512
#define D_N 512
#define C_N 64000
#define S_SCALE 64.0f
#define MARGIN 0.5f
#define EPS_C 1e-7f

typedef unsigned short ushort_t;
typedef __attribute__((ext_vector_type(8))) short short8;   // 8 bf16 (4 VGPRs)
typedef __attribute__((ext_vector_type(4))) float floatx4;  // MFMA acc

__device__ __forceinline__ ushort_t f2bf(float f) {
    unsigned int u = __float_as_uint(f);
    u += 0x7fffu + ((u >> 16) & 1u);  // round-to-nearest-even
    return (ushort_t)(u >> 16);
}

// Normalize x rows -> bf16 xn (blocks 0..127, 4 rows/block) and zero
// rowsum (block 128).
__global__ void xprep_kernel(const float* __restrict__ x,
                             ushort_t* __restrict__ xn,
                             float* __restrict__ rowsum) {
    int b = blockIdx.x;
    int t = threadIdx.x;
    if (b == 128) {
        rowsum[t] = 0.0f;
        rowsum[t + 256] = 0.0f;
        return;
    }
    int row  = b * 4 + (t >> 6);
    int lane = t & 63;
    const float4* p = (const float4*)(x + (size_t)row * D_N);
    float4 v0 = p[lane];        // contiguous 1 KB segment
    float4 v1 = p[lane + 64];   // second 1 KB segment
    float ss = v0.x*v0.x + v0.y*v0.y + v0.z*v0.z + v0.w*v0.w
             + v1.x*v1.x + v1.y*v1.y + v1.z*v1.z + v1.w*v1.w;
#pragma unroll
    for (int off = 32; off > 0; off >>= 1) ss += __shfl_xor(ss, off);
    float sc = 1.0f / fmaxf(sqrtf(ss), 1e-12f);
    ushort_t* dst = xn + (size_t)row * D_N;
    uint2 o0, o1;
    o0.x = (unsigned)f2bf(v0.x*sc) | ((unsigned)f2bf(v0.y*sc) << 16);
    o0.y = (unsigned)f2bf(v0.z*sc) | ((unsigned)f2bf(v0.w*sc) << 16);
    o1.x = (unsigned)f2bf(v1.x*sc) | ((unsigned)f2bf(v1.y*sc) << 16);
    o1.y = (unsigned)f2bf(v1.z*sc) | ((unsigned)f2bf(v1.w*sc) << 16);
    *(uint2*)(dst + lane * 4)       = o0;
    *(uint2*)(dst + 256 + lane * 4) = o1;
}

__device__ __forceinline__ void g2lds16(const ushort_t* g, ushort_t* l) {
    __builtin_amdgcn_global_load_lds(
        (const __attribute__((address_space(1))) void*)g,
        (__attribute__((address_space(3))) void*)l, 16, 0, 0);
}

// One block = 64 classes x all 512 batch rows. 512 threads (8 waves),
// wave w covers output rows [w*64, w*64+64), cols [0,64) -> 4x4 frags.
// sW layout: elem addr = kchunk*512 + (row ^ (kchunk&7))*8 + (k&7);
// the XOR swizzle makes both phase-0 writes (fixed row, lanes=kchunk)
// and frag reads (fixed kchunk, lanes=row) bank-uniform.
__global__ __launch_bounds__(512, 2)
void gemm_fused_kernel(const float* __restrict__ W,
                       const ushort_t* __restrict__ xn,
                       const int* __restrict__ y,
                       float* __restrict__ rowsum,
                       float* __restrict__ tgt) {
    __shared__ ushort_t sW[64 * 512];      // 64 KB resident B operand
    __shared__ ushort_t sA[2 * 512 * 32];  // 64 KB double-buffered A tiles

    int t    = threadIdx.x;
    int lane = t & 63;
    int w    = t >> 6;     // wave 0..7
    int lq   = lane >> 4;  // quad
    int lc   = lane & 15;
    int cn0  = blockIdx.x * 64;

    // ---- Phase 0: load+normalize this block's 64 W rows into sW ----
    // wave w: rows w*8 .. w*8+7; lane covers k = lane*8..lane*8+7 (so the
    // packed 8 bf16 form one ds_write_b128).
#pragma unroll
    for (int rr = 0; rr < 8; ++rr) {
        int row = w * 8 + rr;
        const float4* p = (const float4*)(W + (size_t)(cn0 + row) * D_N);
        float4 a = p[lane * 2];
        float4 b = p[lane * 2 + 1];
        float ss = a.x*a.x + a.y*a.y + a.z*a.z + a.w*a.w
                 + b.x*b.x + b.y*b.y + b.z*b.z + b.w*b.w;
#pragma unroll
        for (int off = 32; off > 0; off >>= 1) ss += __shfl_xor(ss, off);
        float sc = 1.0f / fmaxf(sqrtf(ss), 1e-12f);
        uint4 o;
        o.x = (unsigned)f2bf(a.x*sc) | ((unsigned)f2bf(a.y*sc) << 16);
        o.y = (unsigned)f2bf(a.z*sc) | ((unsigned)f2bf(a.w*sc) << 16);
        o.z = (unsigned)f2bf(b.x*sc) | ((unsigned)f2bf(b.y*sc) << 16);
        o.w = (unsigned)f2bf(b.z*sc) | ((unsigned)f2bf(b.w*sc) << 16);
        int kc = lane;                 // kchunk 0..63
        int rs = row ^ (kc & 7);       // swizzled slot
        *((uint4*)(sW + kc * 512 + rs * 8)) = o;
    }

    // ---- Stage A tile 0 (rows 0..511, k 0..31) ----
    const ushort_t* gA = xn + (size_t)(t >> 2) * D_N + (t & 3) * 8;
#pragma unroll
    for (int c = 0; c < 4; ++c)
        g2lds16(gA + (size_t)c * 128 * D_N, sA + (t + c * 512) * 8);
    __syncthreads();  // drains phase-0 ds_writes AND tile-0 g2lds

    floatx4 acc[4][4];
#pragma unroll
    for (int i = 0; i < 4; i++)
#pragma unroll
        for (int j = 0; j < 4; j++) acc[i][j] = (floatx4){0.f, 0.f, 0.f, 0.f};

    int fragA_base = (w * 64 + lc) * 32 + lq * 8;  // + tm*512 + buf

    for (int k = 0; k < 16; ++k) {
        int cur = (k & 1) * 16384;
        if (k < 15) {
            int nxt = ((k + 1) & 1) * 16384;
            int kk  = (k + 1) * 32;
#pragma unroll
            for (int c = 0; c < 4; ++c)
                g2lds16(gA + (size_t)c * 128 * D_N + kk,
                        sA + nxt + (t + c * 512) * 8);
        }
        short8 af[4], bfr[4];
#pragma unroll
        for (int tm = 0; tm < 4; tm++)
            af[tm] = *(const short8*)(sA + cur + fragA_base + tm * 512);
#pragma unroll
        for (int tn = 0; tn < 4; tn++) {
            int kc = k * 4 + lq;
            int rs = (tn * 16 + lc) ^ (kc & 7);
            bfr[tn] = *(const short8*)(sW + kc * 512 + rs * 8);
        }
#pragma unroll
        for (int tm = 0; tm < 4; tm++)
#pragma unroll
            for (int tn = 0; tn < 4; tn++)
                acc[tm][tn] = __builtin_amdgcn_mfma_f32_16x16x32_bf16(
                    af[tm], bfr[tn], acc[tm][tn], 0, 0, 0);
        __syncthreads();  // release buffer `cur`; drains next prefetch
    }

    // ---- Epilogue. C/D layout: col = lane&15, row = lq*4 + reg. ----
    // Each lrow is produced by exactly one (wave, tm, lq, r) -> the lc==0
    // lane can plain-store into the reused sA region (no LDS atomics).
    float* rowacc = (float*)sA;  // safe: loop ended with __syncthreads
#pragma unroll
    for (int tm = 0; tm < 4; tm++) {
#pragma unroll
        for (int r = 0; r < 4; r++) {
            int lrow = w * 64 + tm * 16 + lq * 4 + r;  // 0..511
            int yv   = y[lrow];
            float esum = 0.0f;
#pragma unroll
            for (int tn = 0; tn < 4; tn++) {
                int gcol = cn0 + tn * 16 + lc;
                float theta = acc[tm][tn][r];
                if (gcol == yv) {
                    tgt[lrow] = theta;  // exactly one writer device-wide
                } else {
                    esum += __expf(S_SCALE * theta);
                }
            }
#pragma unroll
            for (int off = 1; off < 16; off <<= 1) esum += __shfl_xor(esum, off);
            if (lc == 0) rowacc[lrow] = esum;
        }
    }
    __syncthreads();
    atomicAdd(&rowsum[t], rowacc[t]);  // 512 coalesced adds per block
}

__global__ void finalize_kernel(const float* __restrict__ rowsum,
                                const float* __restrict__ tgt,
                                float* __restrict__ out) {
    __shared__ float red[256];
    int t = threadIdx.x;
    float s = 0.0f;
    for (int r = t; r < B_N; r += 256) {
        float tv = tgt[r];
        tv = fminf(fmaxf(tv, -1.0f + EPS_C), 1.0f - EPS_C);
        float num = S_SCALE * cosf(acosf(tv) + MARGIN);
        float den = expf(num) + rowsum[r];
        s += num - logf(den);
    }
    red[t] = s;
    __syncthreads();
    for (int o = 128; o > 0; o >>= 1) {
        if (t < o) red[t] += red[t + o];
        __syncthreads();
    }
    if (t == 0) out[0] = -red[0] / (float)B_N;
}

extern "C" void kernel_launch(void* const* d_in, const int* in_sizes, int n_in,
                              void* d_out, int out_size, void* d_ws, size_t ws_size,
                              hipStream_t stream) {
    const float* x = (const float*)d_in[0];
    const int*   y = (const int*)d_in[1];
    const float* W = (const float*)d_in[2];
    float* out = (float*)d_out;

    char* ws = (char*)d_ws;
    ushort_t* xn = (ushort_t*)ws;                  // 512 KB
    float* rowsum = (float*)(ws + 524288);         // 2 KB
    float* tgt    = rowsum + B_N;                  // 2 KB

    xprep_kernel<<<129, 256, 0, stream>>>(x, xn, rowsum);
    gemm_fused_kernel<<<C_N / 64, 512, 0, stream>>>(W, xn, y, rowsum, tgt);
    finalize_kernel<<<1, 256, 0, stream>>>(rowsum, tgt, out);
}

// Round 4
// 261.675 us; speedup vs baseline: 1.0295x; 1.0295x over previous
//
#include <hip/hip_runtime.h>

// ArcFace loss, MI355X. B=512, D=512, C=64000, s=64, m=0.5.
// R4: W read once into LDS-resident B operand (64 KB -> 2 blocks/CU);
// A-fragments read directly from L2-resident xn (no sA, no K-loop
// barriers); epilogue atomics spread over 16 rowsum replicas.

#define B_N 512
#define D_N 512
#define C_N 64000
#define S_SCALE 64.0f
#define MARGIN 0.5f
#define EPS_C 1e-7f
#define NREP 16

typedef unsigned short ushort_t;
typedef __attribute__((ext_vector_type(8))) short short8;   // 8 bf16 (4 VGPRs)
typedef __attribute__((ext_vector_type(4))) float floatx4;  // MFMA acc

__device__ __forceinline__ ushort_t f2bf(float f) {
    unsigned int u = __float_as_uint(f);
    u += 0x7fffu + ((u >> 16) & 1u);  // round-to-nearest-even
    return (ushort_t)(u >> 16);
}

// Normalize x rows -> bf16 xn (blocks 0..127, 4 rows/block) and zero the
// 16 rowsum replicas (block 128).
__global__ void xprep_kernel(const float* __restrict__ x,
                             ushort_t* __restrict__ xn,
                             float* __restrict__ rowsumR) {
    int b = blockIdx.x;
    int t = threadIdx.x;
    if (b == 128) {
#pragma unroll
        for (int i = 0; i < NREP * B_N / 256; ++i)
            rowsumR[i * 256 + t] = 0.0f;
        return;
    }
    int row  = b * 4 + (t >> 6);
    int lane = t & 63;
    const float4* p = (const float4*)(x + (size_t)row * D_N);
    float4 v0 = p[lane];        // contiguous 1 KB segment
    float4 v1 = p[lane + 64];   // second 1 KB segment
    float ss = v0.x*v0.x + v0.y*v0.y + v0.z*v0.z + v0.w*v0.w
             + v1.x*v1.x + v1.y*v1.y + v1.z*v1.z + v1.w*v1.w;
#pragma unroll
    for (int off = 32; off > 0; off >>= 1) ss += __shfl_xor(ss, off);
    float sc = 1.0f / fmaxf(sqrtf(ss), 1e-12f);
    ushort_t* dst = xn + (size_t)row * D_N;
    uint2 o0, o1;
    o0.x = (unsigned)f2bf(v0.x*sc) | ((unsigned)f2bf(v0.y*sc) << 16);
    o0.y = (unsigned)f2bf(v0.z*sc) | ((unsigned)f2bf(v0.w*sc) << 16);
    o1.x = (unsigned)f2bf(v1.x*sc) | ((unsigned)f2bf(v1.y*sc) << 16);
    o1.y = (unsigned)f2bf(v1.z*sc) | ((unsigned)f2bf(v1.w*sc) << 16);
    *(uint2*)(dst + lane * 4)       = o0;
    *(uint2*)(dst + 256 + lane * 4) = o1;
}

// One block = 64 classes x all 512 batch rows. 8 waves; wave w owns output
// rows [w*64, w*64+64) x cols [0,64) -> 4x4 mfma_f32_16x16x32_bf16 frags.
// sW layout (XOR swizzle, R3-verified): addr = kc*512 + (row^(kc&7))*8 + k&7.
// K-loop: af from global xn (L2), bfr from sW -- NO barriers.
__global__ __launch_bounds__(512, 4)
void gemm_fused_kernel(const float* __restrict__ W,
                       const ushort_t* __restrict__ xn,
                       const int* __restrict__ y,
                       float* __restrict__ rowsumR,
                       float* __restrict__ tgt) {
    __shared__ ushort_t sW[64 * 512];  // 64 KB resident B operand

    int t    = threadIdx.x;
    int lane = t & 63;
    int w    = t >> 6;     // wave 0..7
    int lq   = lane >> 4;  // quad
    int lc   = lane & 15;
    int cn0  = blockIdx.x * 64;

    // ---- Phase 0: load + normalize this block's 64 W rows into sW ----
#pragma unroll
    for (int rr = 0; rr < 8; ++rr) {
        int row = w * 8 + rr;
        const float4* p = (const float4*)(W + (size_t)(cn0 + row) * D_N);
        float4 a = p[lane * 2];
        float4 b = p[lane * 2 + 1];
        float ss = a.x*a.x + a.y*a.y + a.z*a.z + a.w*a.w
                 + b.x*b.x + b.y*b.y + b.z*b.z + b.w*b.w;
#pragma unroll
        for (int off = 32; off > 0; off >>= 1) ss += __shfl_xor(ss, off);
        float sc = 1.0f / fmaxf(sqrtf(ss), 1e-12f);
        uint4 o;
        o.x = (unsigned)f2bf(a.x*sc) | ((unsigned)f2bf(a.y*sc) << 16);
        o.y = (unsigned)f2bf(a.z*sc) | ((unsigned)f2bf(a.w*sc) << 16);
        o.z = (unsigned)f2bf(b.x*sc) | ((unsigned)f2bf(b.y*sc) << 16);
        o.w = (unsigned)f2bf(b.z*sc) | ((unsigned)f2bf(b.w*sc) << 16);
        int kc = lane;
        int rs = row ^ (kc & 7);
        *((uint4*)(sW + kc * 512 + rs * 8)) = o;
    }
    __syncthreads();  // sW ready; only barrier before epilogue

    floatx4 acc[4][4];
#pragma unroll
    for (int i = 0; i < 4; i++)
#pragma unroll
        for (int j = 0; j < 4; j++) acc[i][j] = (floatx4){0.f, 0.f, 0.f, 0.f};

    // A-frag row base pointers: lane lc picks row, lq picks k-subchunk.
    const ushort_t* rowp[4];
#pragma unroll
    for (int tm = 0; tm < 4; tm++)
        rowp[tm] = xn + (size_t)(w * 64 + tm * 16 + lc) * D_N + lq * 8;

    for (int k = 0; k < 16; ++k) {
        short8 af[4], bfr[4];
#pragma unroll
        for (int tm = 0; tm < 4; tm++)
            af[tm] = *(const short8*)(rowp[tm] + k * 32);
        int kc = k * 4 + lq;
#pragma unroll
        for (int tn = 0; tn < 4; tn++) {
            int rs = (tn * 16 + lc) ^ (kc & 7);
            bfr[tn] = *(const short8*)(sW + kc * 512 + rs * 8);
        }
#pragma unroll
        for (int tm = 0; tm < 4; tm++)
#pragma unroll
            for (int tn = 0; tn < 4; tn++)
                acc[tm][tn] = __builtin_amdgcn_mfma_f32_16x16x32_bf16(
                    af[tm], bfr[tn], acc[tm][tn], 0, 0, 0);
    }

    // ---- Epilogue. C/D layout: col = lane&15, row = lq*4 + reg. ----
    __syncthreads();                 // all waves done reading sW
    float* rowacc = (float*)sW;      // reuse LDS; each lrow: 1 writer
#pragma unroll
    for (int tm = 0; tm < 4; tm++) {
#pragma unroll
        for (int r = 0; r < 4; r++) {
            int lrow = w * 64 + tm * 16 + lq * 4 + r;  // 0..511, unique
            int yv   = y[lrow];
            float esum = 0.0f;
#pragma unroll
            for (int tn = 0; tn < 4; tn++) {
                int gcol = cn0 + tn * 16 + lc;
                float theta = acc[tm][tn][r];
                if (gcol == yv) {
                    tgt[lrow] = theta;  // exactly one writer device-wide
                } else {
                    esum += __expf(S_SCALE * theta);
                }
            }
#pragma unroll
            for (int off = 1; off < 16; off <<= 1) esum += __shfl_xor(esum, off);
            if (lc == 0) rowacc[lrow] = esum;
        }
    }
    __syncthreads();
    // one coalesced atomic per row per block, spread over 16 replicas
    atomicAdd(&rowsumR[(blockIdx.x & (NREP - 1)) * B_N + t], rowacc[t]);
}

__global__ void finalize_kernel(const float* __restrict__ rowsumR,
                                const float* __restrict__ tgt,
                                float* __restrict__ out) {
    __shared__ float red[256];
    int t = threadIdx.x;
    float s = 0.0f;
    for (int r = t; r < B_N; r += 256) {
        float rs = 0.0f;
#pragma unroll
        for (int i = 0; i < NREP; ++i) rs += rowsumR[i * B_N + r];
        float tv = tgt[r];
        tv = fminf(fmaxf(tv, -1.0f + EPS_C), 1.0f - EPS_C);
        float num = S_SCALE * cosf(acosf(tv) + MARGIN);
        float den = expf(num) + rs;
        s += num - logf(den);
    }
    red[t] = s;
    __syncthreads();
    for (int o = 128; o > 0; o >>= 1) {
        if (t < o) red[t] += red[t + o];
        __syncthreads();
    }
    if (t == 0) out[0] = -red[0] / (float)B_N;
}

extern "C" void kernel_launch(void* const* d_in, const int* in_sizes, int n_in,
                              void* d_out, int out_size, void* d_ws, size_t ws_size,
                              hipStream_t stream) {
    const float* x = (const float*)d_in[0];
    const int*   y = (const int*)d_in[1];
    const float* W = (const float*)d_in[2];
    float* out = (float*)d_out;

    char* ws = (char*)d_ws;
    ushort_t* xn    = (ushort_t*)ws;                    // 512 KB
    float* rowsumR  = (float*)(ws + 524288);            // 32 KB (16 replicas)
    float* tgt      = rowsumR + NREP * B_N;             // 2 KB

    xprep_kernel<<<129, 256, 0, stream>>>(x, xn, rowsumR);
    gemm_fused_kernel<<<C_N / 64, 512, 0, stream>>>(W, xn, y, rowsumR, tgt);
    finalize_kernel<<<1, 256, 0, stream>>>(rowsumR, tgt, out);
}

// Round 5
// 226.940 us; speedup vs baseline: 1.1871x; 1.1531x over previous
//
#include <hip/hip_runtime.h>

// ArcFace loss, MI355X. B=512, D=512, C=64000, s=64, m=0.5.
// R5: A-operand (x-hat) stored FRAGMENT-LINEAR: xnT[kc][row][8] so each
// MFMA A-frag load is 4x256B contiguous full-line segments instead of
// 16x64B half-line segments (R4's L2-request-rate bottleneck: ~8.2M
// line-requests ~= the whole 121 us). W read once into LDS per block.

#define B_N 512
#define D_N 512
#define C_N 64000
#define S_SCALE 64.0f
#define MARGIN 0.5f
#define EPS_C 1e-7f
#define NREP 16

typedef unsigned short ushort_t;
typedef __attribute__((ext_vector_type(8))) short short8;   // 8 bf16 (4 VGPRs)
typedef __attribute__((ext_vector_type(4))) float floatx4;  // MFMA acc

__device__ __forceinline__ ushort_t f2bf(float f) {
    unsigned int u = __float_as_uint(f);
    u += 0x7fffu + ((u >> 16) & 1u);  // round-to-nearest-even
    return (ushort_t)(u >> 16);
}

// Normalize x rows -> bf16 in fragment-linear layout:
//   xnT element addr = (kc*512 + row)*8 + j,  kc = k/8 in [0,64), j = k%8.
// Lane `lane` of a row packs kc=lane as one uint4 -> one 16 B store.
// Blocks 0..127: 4 rows each. Block 128: zero the rowsum replicas.
__global__ void xprep_kernel(const float* __restrict__ x,
                             ushort_t* __restrict__ xnT,
                             float* __restrict__ rowsumR) {
    int b = blockIdx.x;
    int t = threadIdx.x;
    if (b == 128) {
#pragma unroll
        for (int i = 0; i < NREP * B_N / 256; ++i)
            rowsumR[i * 256 + t] = 0.0f;
        return;
    }
    int row  = b * 4 + (t >> 6);
    int lane = t & 63;
    const float4* p = (const float4*)(x + (size_t)row * D_N);
    float4 v0 = p[lane * 2];        // elems [lane*8 .. lane*8+3]
    float4 v1 = p[lane * 2 + 1];    // elems [lane*8+4 .. lane*8+7]
    float ss = v0.x*v0.x + v0.y*v0.y + v0.z*v0.z + v0.w*v0.w
             + v1.x*v1.x + v1.y*v1.y + v1.z*v1.z + v1.w*v1.w;
#pragma unroll
    for (int off = 32; off > 0; off >>= 1) ss += __shfl_xor(ss, off);
    float sc = 1.0f / fmaxf(sqrtf(ss), 1e-12f);
    uint4 o;
    o.x = (unsigned)f2bf(v0.x*sc) | ((unsigned)f2bf(v0.y*sc) << 16);
    o.y = (unsigned)f2bf(v0.z*sc) | ((unsigned)f2bf(v0.w*sc) << 16);
    o.z = (unsigned)f2bf(v1.x*sc) | ((unsigned)f2bf(v1.y*sc) << 16);
    o.w = (unsigned)f2bf(v1.z*sc) | ((unsigned)f2bf(v1.w*sc) << 16);
    // kc = lane; 16 B store at ((lane*512)+row)*16 bytes (scattered, tiny)
    *((uint4*)(xnT + ((size_t)(lane << 9) + row) * 8)) = o;
}

// One block = 64 classes x all 512 batch rows. 8 waves; wave w owns rows
// [w*64, w*64+64) x cols [0,64) as 4x4 mfma_f32_16x16x32_bf16 frags.
// sW (XOR swizzle): addr = kc*512 + (row^(kc&7))*8 + k&7. A-frags from
// global xnT (L2-resident, full-line coalesced); NO K-loop barriers.
__global__ __launch_bounds__(512, 4)
void gemm_fused_kernel(const float* __restrict__ W,
                       const ushort_t* __restrict__ xnT,
                       const int* __restrict__ y,
                       float* __restrict__ rowsumR,
                       float* __restrict__ tgt) {
    __shared__ ushort_t sW[64 * 512];  // 64 KB resident B operand

    int t    = threadIdx.x;
    int lane = t & 63;
    int w    = t >> 6;     // wave 0..7
    int lq   = lane >> 4;  // quad
    int lc   = lane & 15;
    int cn0  = blockIdx.x * 64;

    // ---- Phase 0: load + normalize this block's 64 W rows into sW ----
#pragma unroll
    for (int rr = 0; rr < 8; ++rr) {
        int row = w * 8 + rr;
        const float4* p = (const float4*)(W + (size_t)(cn0 + row) * D_N);
        float4 a = p[lane * 2];
        float4 b = p[lane * 2 + 1];
        float ss = a.x*a.x + a.y*a.y + a.z*a.z + a.w*a.w
                 + b.x*b.x + b.y*b.y + b.z*b.z + b.w*b.w;
#pragma unroll
        for (int off = 32; off > 0; off >>= 1) ss += __shfl_xor(ss, off);
        float sc = 1.0f / fmaxf(sqrtf(ss), 1e-12f);
        uint4 o;
        o.x = (unsigned)f2bf(a.x*sc) | ((unsigned)f2bf(a.y*sc) << 16);
        o.y = (unsigned)f2bf(a.z*sc) | ((unsigned)f2bf(a.w*sc) << 16);
        o.z = (unsigned)f2bf(b.x*sc) | ((unsigned)f2bf(b.y*sc) << 16);
        o.w = (unsigned)f2bf(b.z*sc) | ((unsigned)f2bf(b.w*sc) << 16);
        int kc = lane;
        int rs = row ^ (kc & 7);
        *((uint4*)(sW + kc * 512 + rs * 8)) = o;
    }
    __syncthreads();  // sW ready; only barrier before epilogue

    floatx4 acc[4][4];
#pragma unroll
    for (int i = 0; i < 4; i++)
#pragma unroll
        for (int j = 0; j < 4; j++) acc[i][j] = (floatx4){0.f, 0.f, 0.f, 0.f};

    // A-frag pointers into fragment-linear xnT. For iteration k, lane
    // (lq,lc), tile tm: elems at ((k*4+lq)*512 + w*64+tm*16+lc)*8.
    // Within one load: 16 lc-lanes x 16 B = 256 B contiguous per lq.
    const ushort_t* apT[4];
#pragma unroll
    for (int tm = 0; tm < 4; tm++)
        apT[tm] = xnT + ((size_t)lq * 512 + w * 64 + tm * 16 + lc) * 8;

    for (int k = 0; k < 16; ++k) {
        short8 af[4], bfr[4];
#pragma unroll
        for (int tm = 0; tm < 4; tm++)
            af[tm] = *(const short8*)(apT[tm] + k * 16384);  // k*4*512*8
        int kc = k * 4 + lq;
#pragma unroll
        for (int tn = 0; tn < 4; tn++) {
            int rs = (tn * 16 + lc) ^ (kc & 7);
            bfr[tn] = *(const short8*)(sW + kc * 512 + rs * 8);
        }
#pragma unroll
        for (int tm = 0; tm < 4; tm++)
#pragma unroll
            for (int tn = 0; tn < 4; tn++)
                acc[tm][tn] = __builtin_amdgcn_mfma_f32_16x16x32_bf16(
                    af[tm], bfr[tn], acc[tm][tn], 0, 0, 0);
    }

    // ---- Epilogue. C/D layout: col = lane&15, row = lq*4 + reg. ----
    __syncthreads();                 // all waves done reading sW
    float* rowacc = (float*)sW;      // reuse LDS; each lrow: 1 writer
#pragma unroll
    for (int tm = 0; tm < 4; tm++) {
#pragma unroll
        for (int r = 0; r < 4; r++) {
            int lrow = w * 64 + tm * 16 + lq * 4 + r;  // 0..511, unique
            int yv   = y[lrow];
            float esum = 0.0f;
#pragma unroll
            for (int tn = 0; tn < 4; tn++) {
                int gcol = cn0 + tn * 16 + lc;
                float theta = acc[tm][tn][r];
                if (gcol == yv) {
                    tgt[lrow] = theta;  // exactly one writer device-wide
                } else {
                    esum += __expf(S_SCALE * theta);
                }
            }
#pragma unroll
            for (int off = 1; off < 16; off <<= 1) esum += __shfl_xor(esum, off);
            if (lc == 0) rowacc[lrow] = esum;
        }
    }
    __syncthreads();
    atomicAdd(&rowsumR[(blockIdx.x & (NREP - 1)) * B_N + t], rowacc[t]);
}

__global__ void finalize_kernel(const float* __restrict__ rowsumR,
                                const float* __restrict__ tgt,
                                float* __restrict__ out) {
    __shared__ float red[256];
    int t = threadIdx.x;
    float s = 0.0f;
    for (int r = t; r < B_N; r += 256) {
        float rs = 0.0f;
#pragma unroll
        for (int i = 0; i < NREP; ++i) rs += rowsumR[i * B_N + r];
        float tv = tgt[r];
        tv = fminf(fmaxf(tv, -1.0f + EPS_C), 1.0f - EPS_C);
        float num = S_SCALE * cosf(acosf(tv) + MARGIN);
        float den = expf(num) + rs;
        s += num - logf(den);
    }
    red[t] = s;
    __syncthreads();
    for (int o = 128; o > 0; o >>= 1) {
        if (t < o) red[t] += red[t + o];
        __syncthreads();
    }
    if (t == 0) out[0] = -red[0] / (float)B_N;
}

extern "C" void kernel_launch(void* const* d_in, const int* in_sizes, int n_in,
                              void* d_out, int out_size, void* d_ws, size_t ws_size,
                              hipStream_t stream) {
    const float* x = (const float*)d_in[0];
    const int*   y = (const int*)d_in[1];
    const float* W = (const float*)d_in[2];
    float* out = (float*)d_out;

    char* ws = (char*)d_ws;
    ushort_t* xnT   = (ushort_t*)ws;                    // 512 KB (frag-linear)
    float* rowsumR  = (float*)(ws + 524288);            // 32 KB (16 replicas)
    float* tgt      = rowsumR + NREP * B_N;             // 2 KB

    xprep_kernel<<<129, 256, 0, stream>>>(x, xnT, rowsumR);
    gemm_fused_kernel<<<C_N / 64, 512, 0, stream>>>(W, xnT, y, rowsumR, tgt);
    finalize_kernel<<<1, 256, 0, stream>>>(rowsumR, tgt, out);
}